// Round 5
// baseline (452.852 us; speedup 1.0000x reference)
//
#include <hip/hip_runtime.h>
#include <math.h>

// B=256, T=2560, D=128, G=64 groups, sizes cycle 16/32/48/64.
// Supergroup of 4 groups spans 160 rows; offsets within supergroup: 0,16,48,96.
// Load balance: each wave handles a PAIR of groups totaling 80 rows:
//   pair 0: sizes {16, 64}  (offsets 0, 96)
//   pair 1: sizes {32, 48}  (offsets 16, 48)
// => every wave does exactly 10 chunks of 8 rows. 2048 blocks = 8/CU x 256 CU.
constexpr int D = 128;
constexpr int B = 256;
constexpr int T = 2560;
constexpr int G = 64;
constexpr int R = 8;    // rows per chunk
constexpr int NCH = 10; // chunks per wave (80 rows)

__global__ __launch_bounds__(256, 8) void ragged_attn_wave(
    const float* __restrict__ s_i,     // [B, D]
    const float* __restrict__ theta,   // [B, T, D]
    float* __restrict__ out)           // [B, G, D]
{
    const int w    = threadIdx.x >> 6;      // wave in block: 0..3
    const int lane = threadIdx.x & 63;
    const int b    = blockIdx.x >> 3;
    const int q    = (blockIdx.x & 7) * 2 + (w >> 1);  // supergroup 0..15
    const int p    = w & 1;                 // pair within supergroup

    const int gmA  = p;                     // 0 or 1  -> S=16 / S=32
    const int gmB  = 3 - p;                 // 3 or 2  -> S=64 / S=48
    const int SA   = 16 * (gmA + 1);
    const int nchA = SA >> 3;               // 2 or 4
    const int baseA = q * 160 + (gmA * (gmA + 1) / 2) * 16;  // +0 or +16
    const int baseB = q * 160 + (gmB * (gmB + 1) / 2) * 16;  // +96 or +48

    __shared__ float tile[4][R * 128];      // 4 KB per wave, wave-private
    __shared__ float u_sh[4][R];

    const int h = lane >> 5;                // row parity within load pair
    const int c = lane & 31;                // float4 column

    const float4 s4 = ((const float4*)(s_i + (size_t)b * D))[c];
    const float4* tbase = (const float4*)(theta + (size_t)b * T * D);

    // row base of chunk ch in the flat 10-chunk schedule
    auto rowbase = [&](int ch) -> int {
        return (ch < nchA) ? (baseA + ch * R) : (baseB + (ch - nchA) * R);
    };

    float m = -INFINITY, l = 0.0f;
    float acc0 = 0.0f, acc1 = 0.0f;

    // prologue: chunk 0 loads in flight
    float4 rb[4];
    {
        const int r0 = rowbase(0);
        #pragma unroll
        for (int k = 0; k < 4; ++k)
            rb[k] = tbase[(size_t)(r0 + 2 * k + h) * 32 + c];
    }

    for (int ch = 0; ch < NCH; ++ch) {
        // stage chunk to wave-private LDS + fused partial dots
        float dt[4];
        #pragma unroll
        for (int k = 0; k < 4; ++k) {
            const float4 v = rb[k];
            ((float4*)&tile[w][(2 * k + h) * 128])[c] = v;
            dt[k] = v.x * s4.x + v.y * s4.y + v.z * s4.z + v.w * s4.w;
        }
        // prefetch next chunk (overlaps softmax + accumulate below)
        if (ch + 1 < NCH) {
            const int rn = rowbase(ch + 1);
            #pragma unroll
            for (int k = 0; k < 4; ++k)
                rb[k] = tbase[(size_t)(rn + 2 * k + h) * 32 + c];
        }
        // reduce dots across the 32 lanes sharing each row
        #pragma unroll
        for (int k = 0; k < 4; ++k) {
            #pragma unroll
            for (int msk = 16; msk >= 1; msk >>= 1)
                dt[k] += __shfl_xor(dt[k], msk);
        }
        if (c == 0) {
            #pragma unroll
            for (int k = 0; k < 4; ++k)
                u_sh[w][2 * k + h] = dt[k] * (1.0f / 128.0f);
        }
        // same-wave DS ordering; compiler inserts lgkmcnt waits
        float uu[R];
        float cm = -INFINITY;
        #pragma unroll
        for (int t = 0; t < R; ++t) {
            uu[t] = u_sh[w][t];             // broadcast read
            cm = fmaxf(cm, uu[t]);
        }
        const float m_new = fmaxf(m, cm);
        const float alpha = __expf(m - m_new);   // 0 on first chunk of a group
        acc0 *= alpha;
        acc1 *= alpha;
        float se = 0.0f;
        #pragma unroll
        for (int t = 0; t < R; ++t) {
            const float e = __expf(uu[t] - m_new);  // uniform across lanes
            se += e;
            acc0 += e * tile[w][t * 128 + lane];        // 2-way alias: free
            acc1 += e * tile[w][t * 128 + 64 + lane];
        }
        l = l * alpha + se;
        m = m_new;

        // group boundary: finalize + reset
        if (ch == nchA - 1 || ch == NCH - 1) {
            const int gm = (ch == nchA - 1) ? gmA : gmB;
            float* op = out + ((size_t)b * G + q * 4 + gm) * D;
            const float inv_l = 1.0f / l;
            op[lane]      = acc0 * inv_l;   // two 256 B coalesced stores
            op[lane + 64] = acc1 * inv_l;
            m = -INFINITY; l = 0.0f; acc0 = 0.0f; acc1 = 0.0f;
        }
    }
}

extern "C" void kernel_launch(void* const* d_in, const int* in_sizes, int n_in,
                              void* d_out, int out_size, void* d_ws, size_t ws_size,
                              hipStream_t stream) {
    const float* s_i   = (const float*)d_in[0];
    const float* theta = (const float*)d_in[1];
    float* out = (float*)d_out;

    // 2048 blocks x 256 threads: 8192 waves, each covering 2 groups (80 rows)
    ragged_attn_wave<<<dim3(B * 8), 256, 0, stream>>>(s_i, theta, out);
}